// Round 6
// baseline (1200.711 us; speedup 1.0000x reference)
//
#include <hip/hip_runtime.h>
#include <hip/hip_bf16.h>
#include <stdint.h>

#define M_TOTAL 8192
#define K_TOTAL 4096
#define N_TOTAL 16384
#define BM 256
#define BN 256
#define BK 32
#define KT2 (K_TOTAL / BK)             // 128 K-tiles of 32
#define TILE_B 16384                   // packed bytes per 256-row block per K-tile (per operand)
#define BUF_S 32768                    // LDS buffer: A 16KB + B 16KB
#define NBUF 4

typedef __bf16 bf16x8 __attribute__((ext_vector_type(8)));
typedef float f32x4 __attribute__((ext_vector_type(4)));
typedef unsigned short u16;
typedef u16 u16x8 __attribute__((ext_vector_type(8)));

static __device__ __forceinline__ u16 f2bf(float f) {
    unsigned int u = __builtin_bit_cast(unsigned int, f);
    u = (u + 0x7fffu + ((u >> 16) & 1u)) >> 16;   // RNE
    return (u16)u;
}

static __device__ __forceinline__ void async16(const void* g, void* l) {
    __builtin_amdgcn_global_load_lds((const __attribute__((address_space(1))) unsigned int*)g,
                                     (__attribute__((address_space(3))) unsigned int*)l,
                                     16, 0, 0);
}

// ---------------- packing kernels ----------------
// Packed layout per 256-row block (2MB): [kt 0..127][f 0..15][lane 0..63][16B]
// where element (row, k) lives at f=(row>>4)&15, lane=(row&15)|(((k>>3)&3)<<4),
// byte=(k&7)*2. A frag ds_read is then base + lane*16: stride-1, conflict-free.
// Thread j owns output 16B j*8..: decode -> read 8 consecutive elems of src.

__global__ __launch_bounds__(256) void cvt_x_pack(const float* __restrict__ x, u16* __restrict__ xb) {
    long long j = (long long)blockIdx.x * 256 + threadIdx.x;
    int mt = (int)(j >> 17);           // 131072 threads per 256-row block
    int j2 = (int)(j & 131071);
    int kt = j2 >> 10;
    int f  = (j2 >> 6) & 15;
    int l  = j2 & 63;
    int r  = mt * 256 + f * 16 + (l & 15);
    int k0 = kt * 32 + ((l >> 4) << 3);
    const float4* s = reinterpret_cast<const float4*>(x + (size_t)r * K_TOTAL + k0);
    float4 a = s[0], b = s[1];
    u16x8 v;
    v[0] = f2bf(a.x); v[1] = f2bf(a.y); v[2] = f2bf(a.z); v[3] = f2bf(a.w);
    v[4] = f2bf(b.x); v[5] = f2bf(b.y); v[6] = f2bf(b.z); v[7] = f2bf(b.w);
    *reinterpret_cast<u16x8*>(xb + j * 8) = v;
}

__global__ __launch_bounds__(256) void cvt_w_pack(const int* __restrict__ w, u16* __restrict__ wb) {
    long long j = (long long)blockIdx.x * 256 + threadIdx.x;
    int nt = (int)(j >> 17);
    int j2 = (int)(j & 131071);
    int kt = j2 >> 10;
    int f  = (j2 >> 6) & 15;
    int l  = j2 & 63;
    int r  = nt * 256 + f * 16 + (l & 15);
    int k0 = kt * 32 + ((l >> 4) << 3);
    const int4* s = reinterpret_cast<const int4*>(w + (size_t)r * K_TOTAL + k0);
    int4 a = s[0], b = s[1];
    u16x8 v;
    v[0] = f2bf((float)a.x); v[1] = f2bf((float)a.y); v[2] = f2bf((float)a.z); v[3] = f2bf((float)a.w);
    v[4] = f2bf((float)b.x); v[5] = f2bf((float)b.y); v[6] = f2bf((float)b.z); v[7] = f2bf((float)b.w);
    *reinterpret_cast<u16x8*>(wb + j * 8) = v;
}

// ---------------- GEMM: 4-buffer rotation, 1 barrier per K32-tile ----------------
// Per tile t: stage(t+3 -> buf[(t+3)&3]) issued FIRST (latency hides under the
// whole window); 12 stride-1 ds_read_b128 (4 B frags, 8 A frags); 32 MFMA with
// compiler-counted lgkm waits pipelining returns into issue; lgkm0; vmcnt(8)
// (2 tiles of stages stay in flight across the barrier); s_barrier.
// Safety: buf[(t+3)&3] last read in window t-1, certified by its lgkm0+bar;
// tile t's data certified by vmcnt at t-1 + bar.

#define BAR()    { asm volatile("" ::: "memory"); __builtin_amdgcn_s_barrier(); asm volatile("" ::: "memory"); }
#define LGKM0()  asm volatile("s_waitcnt lgkmcnt(0)" ::: "memory")
#define VMC8()   asm volatile("s_waitcnt vmcnt(8)" ::: "memory")
#define VMC4()   asm volatile("s_waitcnt vmcnt(4)" ::: "memory")
#define VMC0()   asm volatile("s_waitcnt vmcnt(0)" ::: "memory")
#define PRIO1()  __builtin_amdgcn_s_setprio(1)
#define PRIO0()  __builtin_amdgcn_s_setprio(0)

#define STG(ts, so) { \
    async16(aS + (size_t)(ts)*TILE_B + tid*16,        ldsc + (so) + tid*16); \
    async16(aS + (size_t)(ts)*TILE_B + 8192 + tid*16, ldsc + (so) + 8192 + tid*16); \
    async16(bS + (size_t)(ts)*TILE_B + tid*16,        ldsc + (so) + 16384 + tid*16); \
    async16(bS + (size_t)(ts)*TILE_B + 8192 + tid*16, ldsc + (so) + 24576 + tid*16); }

#define TILE_BODY(bo, so, ts, dostg, VMW, dobar) { \
    if (dostg) { STG(ts, so); } \
    bf16x8 bfr[4], afr[8]; \
    _Pragma("unroll") \
    for (int ni = 0; ni < 4; ++ni) bfr[ni] = *(const bf16x8*)(bRd + (bo) + ni * 1024); \
    _Pragma("unroll") \
    for (int mi = 0; mi < 8; ++mi) afr[mi] = *(const bf16x8*)(aRd + (bo) + mi * 1024); \
    PRIO1(); \
    _Pragma("unroll") \
    for (int mi = 0; mi < 8; ++mi) { _Pragma("unroll") \
        for (int ni = 0; ni < 4; ++ni) \
            acc[mi][ni] = __builtin_amdgcn_mfma_f32_16x16x32_bf16(afr[mi], bfr[ni], acc[mi][ni], 0, 0, 0); } \
    PRIO0(); \
    LGKM0(); VMW; \
    if (dobar) BAR(); }

__global__ __launch_bounds__(512, 2) void gemm_kernel(const u16* __restrict__ A,
                                                      const u16* __restrict__ B,
                                                      const float* __restrict__ scale,
                                                      float* __restrict__ out) {
    extern __shared__ char ldsc[];
    const int tid  = threadIdx.x;
    const int lane = tid & 63;
    const int wave = tid >> 6;
    const int wm = wave >> 2;          // 0..1
    const int wn = wave & 3;           // 0..3

    // XCD-aware bijective swizzle (2048 blocks, 8 XCDs, 256-block chunks);
    // mt fastest within chunk -> 32 co-resident blocks/XCD share one B-panel.
    int orig = blockIdx.x;
    int swzid = (orig & 7) * 256 + (orig >> 3);
    int mt = swzid & 31;
    int nt = swzid >> 5;

    const char* aS = (const char*)A + (size_t)mt * (KT2 * TILE_B);
    const char* bS = (const char*)B + (size_t)nt * (KT2 * TILE_B);

    // fragment read bases: stride-1 1KB wave reads (uniform base + lane*16)
    const char* aRd = ldsc + wm * 8192 + lane * 16;           // + bo + mi*1024
    const char* bRd = ldsc + 16384 + wn * 4096 + lane * 16;   // + bo + ni*1024

    f32x4 acc[8][4];
    #pragma unroll
    for (int mi = 0; mi < 8; ++mi)
        #pragma unroll
        for (int ni = 0; ni < 4; ++ni)
            acc[mi][ni] = (f32x4){0.f, 0.f, 0.f, 0.f};

    // prologue: stage tiles 0,1,2 into bufs 0,1,2; certify tile 0; barrier
    STG(0, 0); STG(1, BUF_S); STG(2, 2 * BUF_S);
    VMC8();
    BAR();

    // main: 31 x 4 tiles (t = 0..123), stages t+3 = 3..126
    for (int t = 0; t < 124; t += 4) {
        TILE_BODY(0 * BUF_S, 3 * BUF_S, t + 3, true, VMC8(), true);
        TILE_BODY(1 * BUF_S, 0 * BUF_S, t + 4, true, VMC8(), true);
        TILE_BODY(2 * BUF_S, 1 * BUF_S, t + 5, true, VMC8(), true);
        TILE_BODY(3 * BUF_S, 2 * BUF_S, t + 6, true, VMC8(), true);
    }
    // tail: t = 124 (stages 127), 125, 126, 127
    TILE_BODY(0 * BUF_S, 3 * BUF_S, 127, true,  VMC8(), true);
    TILE_BODY(1 * BUF_S, 0,         0,   false, VMC4(), true);
    TILE_BODY(2 * BUF_S, 0,         0,   false, VMC0(), true);
    TILE_BODY(3 * BUF_S, 0,         0,   false, (void)0, false);

    // epilogue: D row=(lane>>4)*4+j, col=lane&15; scale per output col
    int m0 = mt * BM, n0 = nt * BN;
    int col0 = n0 + wn * 64 + (lane & 15);
    int row0 = m0 + wm * 128 + ((lane >> 4) << 2);
    #pragma unroll
    for (int ni = 0; ni < 4; ++ni) {
        float sc = scale[col0 + ni * 16];
        #pragma unroll
        for (int mi = 0; mi < 8; ++mi) {
            #pragma unroll
            for (int j = 0; j < 4; ++j) {
                out[(size_t)(row0 + mi * 16 + j) * N_TOTAL + (col0 + ni * 16)] = acc[mi][ni][j] * sc;
            }
        }
    }
}

// ---------------- fallback ----------------

__global__ __launch_bounds__(256) void naive_kernel(const float* __restrict__ x, const int* __restrict__ w,
                                                    const float* __restrict__ scale, float* __restrict__ out) {
    int n = blockIdx.x * 256 + threadIdx.x;
    int m = blockIdx.y;
    const float* xr = x + (size_t)m * K_TOTAL;
    const int*   wr = w + (size_t)n * K_TOTAL;
    float acc = 0.f;
    for (int k = 0; k < K_TOTAL; k += 4) {
        float4 xv = *(const float4*)(xr + k);
        int4   wv = *(const int4*)(wr + k);
        acc += xv.x * (float)wv.x + xv.y * (float)wv.y + xv.z * (float)wv.z + xv.w * (float)wv.w;
    }
    out[(size_t)m * N_TOTAL + n] = acc * scale[n];
}

extern "C" void kernel_launch(void* const* d_in, const int* in_sizes, int n_in,
                              void* d_out, int out_size, void* d_ws, size_t ws_size,
                              hipStream_t stream) {
    const float* x     = (const float*)d_in[0];
    const int*   w     = (const int*)d_in[1];
    const float* scale = (const float*)d_in[2];
    float* out = (float*)d_out;

    const size_t xb_bytes = (size_t)M_TOTAL * K_TOTAL * 2;
    const size_t wb_bytes = (size_t)N_TOTAL * K_TOTAL * 2;

    if (ws_size >= xb_bytes + wb_bytes) {
        u16* xb = (u16*)d_ws;
        u16* wb = (u16*)((char*)d_ws + xb_bytes);
        (void)hipFuncSetAttribute((const void*)gemm_kernel,
                                  hipFuncAttributeMaxDynamicSharedMemorySize, NBUF * BUF_S);
        cvt_x_pack<<<(M_TOTAL / 256) * (K_TOTAL / 8), 256, 0, stream>>>(x, xb);
        cvt_w_pack<<<(N_TOTAL / 256) * (K_TOTAL / 8), 256, 0, stream>>>(w, wb);
        gemm_kernel<<<(M_TOTAL / BM) * (N_TOTAL / BN), 512, NBUF * BUF_S, stream>>>(xb, wb, scale, out);
    } else {
        dim3 g(N_TOTAL / 256, M_TOTAL);
        naive_kernel<<<g, 256, 0, stream>>>(x, w, scale, out);
    }
}